// Round 16
// baseline (75.641 us; speedup 1.0000x reference)
//
#include <hip/hip_runtime.h>

#define NB 64
#define NN 1500
#define NM 100
#define NBINS 1280
#define KEEP 128

#define TOTALQ 9720000u        // float4 quads in out (38,880,000 floats / 4)
#define DELTA_FLOATS 31104000u
#define LOGIC_BLOCKS 64
#define FILL_BLOCKS 256        // 1 block/CU, 148 iters/thread — proven 6.4+ TB/s shape
#define GRID_TOTAL (LOGIC_BLOCKS + FILL_BLOCKS)

// ws: 0 posCnt[64] | 256 negCnt[64] | 1024 posSlot[64*128] u32 |
//     33792 negSlot[64*128] u32 | 66560 posDD[64*128] float4   (197,632 B)

// ---------------- K1: logic blocks 0..63 (IoU+selection+lists, ws only) ∥ fill blocks 64..319 ----------------
__global__ __launch_bounds__(256) void k1_fused(
    const float4* __restrict__ roi, const float4* __restrict__ gt,
    const int* __restrict__ gtl, const int* __restrict__ rpos,
    const int* __restrict__ rneg,
    int* __restrict__ posCnt, int* __restrict__ negCnt,
    unsigned int* __restrict__ posSlot, unsigned int* __restrict__ negSlot,
    float4* __restrict__ posDD,
    float4* __restrict__ outq)
{
    __shared__ float4 gtb[NM];
    __shared__ float  gta[NM];
    __shared__ int    gtlL[NM];
    __shared__ int    hist[NBINS];
    __shared__ int    waveTot[4];
    __shared__ int    cnt6[6][4];
    __shared__ int    sstar_s, q_s;
    __shared__ int    cntLds[2];

    int blk = blockIdx.x;
    int tid = threadIdx.x;

    if (blk >= LOGIC_BLOCKS) {
        // proven long-train grid-stride zero-fill (148 iterations/thread)
        unsigned int t = (unsigned int)(blk - LOGIC_BLOCKS) * 256u + (unsigned int)tid;
        const unsigned int stride = FILL_BLOCKS * 256u;
        const float4 z = make_float4(0.f, 0.f, 0.f, 0.f);
        for (unsigned int q = t; q < TOTALQ; q += stride) outq[q] = z;
        return;
    }

    int b = blk;
    int lane = tid & 63, w = tid >> 6;

    if (tid < NM) {
        float4 g = gt[b*NM + tid];
        gtb[tid] = g;
        gta[tid] = (g.z - g.x) * (g.w - g.y);
        gtlL[tid] = gtl[b*NM + tid];
    }
    if (tid < 2) cntLds[tid] = 0;
    __syncthreads();

    // ---- IoU + argmax, scores & roi kept in registers (i = c*256+tid mapping) ----
    float4 roiReg[6];
    int sPos[6], sNeg[6], bestReg[6];
    #pragma unroll
    for (int c = 0; c < 6; ++c) {
        int n = c*256 + tid;
        sPos[c] = 0; sNeg[c] = 0; bestReg[c] = 0;
        roiReg[c] = make_float4(0.f,0.f,0.f,0.f);
        if (n < NN) {
            int idx = b*NN + n;
            float4 r = roi[idx];                   // [y1,x1,y2,x2]
            roiReg[c] = r;
            float by1=r.x, bx1=r.y, by2=r.z, bx2=r.w;
            float barea = (by2-by1)*(bx2-bx1);
            float bestIoU = -1.0f; int bi = 0;
            for (int m = 0; m < NM; ++m) {
                float4 g = gtb[m];
                float xt = fmaxf(bx1, g.y);
                float yt = fmaxf(by1, g.x);
                float xb = fminf(bx2, g.w);
                float yb = fminf(by2, g.z);
                float inter = fmaxf(xb-xt, 0.0f) * fmaxf(yb-yt, 0.0f);
                float uni = (barea + gta[m]) - inter;
                float iou = inter / uni;
                if (iou > bestIoU) { bestIoU = iou; bi = m; }   // first-max argmax
            }
            bestReg[c] = bi;
            sPos[c] = (bestIoU > 0.5f) ? rpos[idx] : 0;
            sNeg[c] = (bestIoU < 0.5f && bestIoU > 0.1f) ? rneg[idx] : 0;
        }
    }

    // ---- barrier-light top-128 select per mask + compact list build (proven fragments) ----
    for (int m = 0; m < 2; ++m) {
        for (int s = tid; s < NBINS; s += 256) hist[s] = 0;
        if (tid == 0) { sstar_s = 0; q_s = 0; }
        __syncthreads();
        #pragma unroll
        for (int c = 0; c < 6; ++c) {
            int s = m ? sNeg[c] : sPos[c];
            if (s > 0) atomicAdd(&hist[s], 1);
        }
        __syncthreads();
        int base = tid*5;
        int p = hist[base]+hist[base+1]+hist[base+2]+hist[base+3]+hist[base+4];
        int myp = p;
        #pragma unroll
        for (int off = 1; off < 64; off <<= 1) {
            int v = __shfl_down(p, off, 64);
            if (lane + off < 64) p += v;
        }
        if (lane == 0) waveTot[w] = p;
        __syncthreads();
        int suffix = p;
        for (int ww = w+1; ww < 4; ++ww) suffix += waveTot[ww];
        int running = suffix - myp;          // count in bins strictly above my range
        for (int s = base+4; s >= base; --s) {
            int c = hist[s];
            if (s >= 1 && c > 0 && running < KEEP && running + c >= KEEP) {
                sstar_s = s; q_s = KEEP - running;    // unique straddle bin
            }
            running += c;
        }
        __syncthreads();
        int sstar = sstar_s, q = q_s;

        bool eqReg[6];
        int  lowReg[6];
        #pragma unroll
        for (int c = 0; c < 6; ++c) {
            int s = m ? sNeg[c] : sPos[c];
            bool eq = (s > 0) && (s == sstar);
            unsigned long long bal = __ballot(eq);
            if (lane == 0) cnt6[c][w] = (int)__popcll(bal);
            eqReg[c]  = eq;
            lowReg[c] = (int)__popcll(bal & ((1ull << lane) - 1ull));
        }
        __syncthreads();
        int cum = 0;
        #pragma unroll
        for (int c = 0; c < 6; ++c) {
            int preC = cum;
            for (int ww = 0; ww < w; ++ww) preC += cnt6[c][ww];
            int E = preC + lowReg[c];       // global index-order rank among ties
            int s = m ? sNeg[c] : sPos[c];
            bool keep = (s > 0) && (s > sstar || (eqReg[c] && E < q));
            if (keep) {
                int idx = b*NN + c*256 + tid;
                int pslot = atomicAdd(&cntLds[m], 1);
                if (m == 0) {
                    int bi = bestReg[c];
                    int lab = gtlL[bi];
                    float4 r = roiReg[c];
                    float4 g = gtb[bi];
                    float bw = r.w - r.y, bh = r.z - r.x;
                    float bcx = r.y + 0.5f*bw, bcy = r.x + 0.5f*bh;
                    float gw = g.w - g.y, gh = g.z - g.x;
                    float gcx = g.y + 0.5f*gw, gcy = g.x + 0.5f*gh;
                    if (bw == 0.0f) bw = 0.001f;
                    if (bh == 0.0f) bh = 0.001f;
                    float dx  = (gw==0.0f) ? 0.0f : (gcx-bcx)/bw;
                    float dy  = (gh==0.0f) ? 0.0f : (gcy-bcy)/bh;
                    float dwv = (gw==0.0f) ? 0.0f : logf(gw/bw);
                    float dhv = (gh==0.0f) ? 0.0f : logf(gh/bh);
                    posSlot[b*KEEP + pslot] = (unsigned int)idx * 81u + (unsigned int)lab;
                    posDD[b*KEEP + pslot] = make_float4(dy/0.1f, dx/0.1f, dhv/0.2f, dwv/0.2f);
                } else {
                    negSlot[b*KEEP + pslot] = (unsigned int)idx * 81u;   // label 0
                }
            }
            cum += cnt6[c][0]+cnt6[c][1]+cnt6[c][2]+cnt6[c][3];
        }
        __syncthreads();   // protects hist/sstar for next mask; cntLds[m] complete
    }
    if (tid == 0) { posCnt[b] = cntLds[0]; negCnt[b] = cntLds[1]; }
}

// ---------------- K2: trivial sparse scatter (ordering via kernel boundary; proven R2/R7 code) ----------------
__global__ __launch_bounds__(256) void k2_scatter(
    const int* __restrict__ posCnt, const int* __restrict__ negCnt,
    const unsigned int* __restrict__ posSlot, const unsigned int* __restrict__ negSlot,
    const float4* __restrict__ posDD, float* __restrict__ out)
{
    int b = blockIdx.x;
    int t = threadIdx.x;
    if (t < KEEP) {
        if (t < posCnt[b]) {
            unsigned int s = posSlot[b*KEEP + t];
            reinterpret_cast<float4*>(out)[s] = posDD[b*KEEP + t];  // delta quad
            out[DELTA_FLOATS + s] = 1.0f;                           // one-hot label
        }
    } else {
        int u = t - KEEP;
        if (u < negCnt[b]) out[DELTA_FLOATS + negSlot[b*KEEP + u]] = 1.0f;
    }
}

extern "C" void kernel_launch(void* const* d_in, const int* in_sizes, int n_in,
                              void* d_out, int out_size, void* d_ws, size_t ws_size,
                              hipStream_t stream) {
    const float4* roi = (const float4*)d_in[0];   // [B,N,4] f32
    const float4* gt  = (const float4*)d_in[1];   // [B,M,4] f32
    const int* gtl  = (const int*)d_in[2];        // [B,M]
    const int* rpos = (const int*)d_in[3];        // [B,N]
    const int* rneg = (const int*)d_in[4];        // [B,N]
    float* out = (float*)d_out;

    char* ws = (char*)d_ws;
    int*          posCnt  = (int*)(ws);
    int*          negCnt  = (int*)(ws + 256);
    unsigned int* posSlot = (unsigned int*)(ws + 1024);
    unsigned int* negSlot = (unsigned int*)(ws + 33792);
    float4*       posDD   = (float4*)(ws + 66560);

    k1_fused <<<GRID_TOTAL, 256, 0, stream>>>(roi, gt, gtl, rpos, rneg,
                                              posCnt, negCnt, posSlot, negSlot, posDD,
                                              (float4*)out);
    k2_scatter<<<NB, 256, 0, stream>>>(posCnt, negCnt, posSlot, negSlot, posDD, out);
}

// Round 17
// 31.796 us; speedup vs baseline: 2.3790x; 2.3790x over previous
//
#include <hip/hip_runtime.h>

#define NB 64
#define NN 1500
#define NM 100
#define NBINS 1280
#define KEEP 128

#define TOTALQ 9720000u        // float4 quads in out (38,880,000 floats / 4)
#define DELTA_FLOATS 31104000u
#define IOU_BLOCKS 384
#define FILL_BLOCKS 256        // 1 block/CU, 148 iters/thread — longest store trains
#define GRID_TOTAL (IOU_BLOCKS + FILL_BLOCKS)

// ws: 0 spos[96000] int | 384000 sneg[96000] int | 768000 lbl[96000] int |
//     1152000 d4[96000] float4   (total 2,688,000 B)

// ---------------- K1: IoU + eager delta (blocks 0..383) + zero-fill (blocks 384..639) ----------------
__global__ __launch_bounds__(256) void k1_fused(
    const float4* __restrict__ roi, const float4* __restrict__ gt,
    const int* __restrict__ gtl, const int* __restrict__ rpos,
    const int* __restrict__ rneg,
    int* __restrict__ spos, int* __restrict__ sneg,
    int* __restrict__ lbl, float4* __restrict__ d4,
    float4* __restrict__ outq)
{
    __shared__ float4 gtb[NM];
    __shared__ float  gta[NM];
    __shared__ int    gtlL[NM];

    int blk = blockIdx.x;
    int tid = threadIdx.x;

    if (blk < IOU_BLOCKS) {
        int b = blk / 6;
        int chunk = blk % 6;
        if (tid < NM) {
            float4 g = gt[b*NM + tid];
            gtb[tid] = g;
            gta[tid] = (g.z - g.x) * (g.w - g.y);
            gtlL[tid] = gtl[b*NM + tid];
        }
        __syncthreads();
        int n = chunk*256 + tid;
        if (n >= NN) return;
        int idx = b*NN + n;
        float4 r = roi[idx];                        // [y1,x1,y2,x2]
        float by1=r.x, bx1=r.y, by2=r.z, bx2=r.w;
        float barea = (by2-by1)*(bx2-bx1);
        float bestIoU = -1.0f; int bestIdx = 0;
        for (int m = 0; m < NM; ++m) {
            float4 g = gtb[m];
            float xt = fmaxf(bx1, g.y);
            float yt = fmaxf(by1, g.x);
            float xb = fminf(bx2, g.w);
            float yb = fminf(by2, g.z);
            float inter = fmaxf(xb-xt, 0.0f) * fmaxf(yb-yt, 0.0f);
            float uni = (barea + gta[m]) - inter;
            float iou = inter / uni;
            if (iou > bestIoU) { bestIoU = iou; bestIdx = m; }  // first-max argmax
        }
        spos[idx] = (bestIoU > 0.5f) ? rpos[idx] : 0;
        sneg[idx] = (bestIoU < 0.5f && bestIoU > 0.1f) ? rneg[idx] : 0;
        if (bestIoU > 0.5f) {
            // eager delta for every pos-eligible row (superset of the kept set)
            float4 g = gtb[bestIdx];
            float bw = bx2 - bx1, bh = by2 - by1;
            float bcx = bx1 + 0.5f*bw, bcy = by1 + 0.5f*bh;
            float gw = g.w - g.y, gh = g.z - g.x;
            float gcx = g.y + 0.5f*gw, gcy = g.x + 0.5f*gh;
            if (bw == 0.0f) bw = 0.001f;
            if (bh == 0.0f) bh = 0.001f;
            float dx  = (gw==0.0f) ? 0.0f : (gcx-bcx)/bw;
            float dy  = (gh==0.0f) ? 0.0f : (gcy-bcy)/bh;
            float dwv = (gw==0.0f) ? 0.0f : logf(gw/bw);
            float dhv = (gh==0.0f) ? 0.0f : logf(gh/bh);
            lbl[idx] = gtlL[bestIdx];
            d4[idx] = make_float4(dy/0.1f, dx/0.1f, dhv/0.2f, dwv/0.2f);
        }
        return;
    }
    // long-running grid-stride zero-fill (148 iterations/thread)
    unsigned int t = (unsigned int)(blk - IOU_BLOCKS) * 256u + (unsigned int)tid;
    const unsigned int stride = FILL_BLOCKS * 256u;
    const float4 z = make_float4(0.f, 0.f, 0.f, 0.f);
    for (unsigned int q = t; q < TOTALQ; q += stride) outq[q] = z;
}

// ---------------- K2: per-(batch,mask) register-resident top-128 select + scatter (unchanged) ----------------
__global__ __launch_bounds__(256) void k2_select(
    const int* __restrict__ sposA, const int* __restrict__ snegA,
    const int* __restrict__ lbl, const float4* __restrict__ d4,
    float* __restrict__ out)
{
    __shared__ int hist[NBINS];
    __shared__ int waveTot[4];
    __shared__ int cnt6[6][4];
    __shared__ int sstar_s, q_s;

    int b = blockIdx.x >> 1;
    int msk = blockIdx.x & 1;              // 0 = pos, 1 = neg
    const int* __restrict__ src = msk ? snegA : sposA;
    int tid = threadIdx.x;
    int lane = tid & 63, w = tid >> 6;

    // register-resident scores, i = c*256+tid mapping throughout
    int sReg[6];
    #pragma unroll
    for (int c = 0; c < 6; ++c) {
        int i = c*256 + tid;
        sReg[c] = (i < NN) ? src[b*NN + i] : 0;
    }
    for (int s = tid; s < NBINS; s += 256) hist[s] = 0;
    if (tid == 0) { sstar_s = 0; q_s = 0; }
    __syncthreads();
    #pragma unroll
    for (int c = 0; c < 6; ++c) {
        int s = sReg[c];
        if (s > 0) atomicAdd(&hist[s], 1);
    }
    __syncthreads();
    // per-thread sum over 5 bins; wave shuffle suffix scan; cross-wave combine
    int base = tid*5;
    int p = hist[base]+hist[base+1]+hist[base+2]+hist[base+3]+hist[base+4];
    int myp = p;
    #pragma unroll
    for (int off = 1; off < 64; off <<= 1) {
        int v = __shfl_down(p, off, 64);
        if (lane + off < 64) p += v;
    }
    if (lane == 0) waveTot[w] = p;
    __syncthreads();
    int suffix = p;
    for (int ww = w+1; ww < 4; ++ww) suffix += waveTot[ww];
    int running = suffix - myp;          // count in bins strictly above my range
    for (int s = base+4; s >= base; --s) {
        int c = hist[s];
        if (s >= 1 && c > 0 && running < KEEP && running + c >= KEEP) {
            sstar_s = s; q_s = KEEP - running;    // unique straddle bin
        }
        running += c;
    }
    __syncthreads();
    int sstar = sstar_s, q = q_s;

    // ordered tie-scan, two passes, 1 barrier between
    bool eqReg[6];
    int  lowReg[6];
    #pragma unroll
    for (int c = 0; c < 6; ++c) {
        int s = sReg[c];
        bool eq = (s > 0) && (s == sstar);
        unsigned long long bal = __ballot(eq);
        if (lane == 0) cnt6[c][w] = (int)__popcll(bal);
        eqReg[c]  = eq;
        lowReg[c] = (int)__popcll(bal & ((1ull << lane) - 1ull));
    }
    __syncthreads();
    bool keepReg[6];
    int cum = 0;
    #pragma unroll
    for (int c = 0; c < 6; ++c) {
        int preC = cum;
        for (int ww = 0; ww < w; ++ww) preC += cnt6[c][ww];
        int E = preC + lowReg[c];       // global index-order rank among ties
        int s = sReg[c];
        keepReg[c] = (s > 0) && (s > sstar || (eqReg[c] && E < q));
        cum += cnt6[c][0]+cnt6[c][1]+cnt6[c][2]+cnt6[c][3];
    }

    // scatter into the (already zero-filled) output
    if (msk == 0) {
        #pragma unroll
        for (int c = 0; c < 6; ++c) {
            if (keepReg[c]) {
                int idx = b*NN + c*256 + tid;
                unsigned int slot = (unsigned int)idx * 81u + (unsigned int)lbl[idx];
                reinterpret_cast<float4*>(out)[slot] = d4[idx];  // delta quad
                out[DELTA_FLOATS + slot] = 1.0f;                 // one-hot label
            }
        }
    } else {
        #pragma unroll
        for (int c = 0; c < 6; ++c) {
            if (keepReg[c])
                out[DELTA_FLOATS + (unsigned int)(b*NN + c*256 + tid) * 81u] = 1.0f; // label 0
        }
    }
}

extern "C" void kernel_launch(void* const* d_in, const int* in_sizes, int n_in,
                              void* d_out, int out_size, void* d_ws, size_t ws_size,
                              hipStream_t stream) {
    const float4* roi = (const float4*)d_in[0];   // [B,N,4] f32
    const float4* gt  = (const float4*)d_in[1];   // [B,M,4] f32
    const int* gtl  = (const int*)d_in[2];        // [B,M]
    const int* rpos = (const int*)d_in[3];        // [B,N]
    const int* rneg = (const int*)d_in[4];        // [B,N]
    float* out = (float*)d_out;

    char* ws = (char*)d_ws;
    int*    spos = (int*)(ws);                // 384000 B
    int*    sneg = (int*)(ws +  384000);      // 384000 B
    int*    lbl  = (int*)(ws +  768000);      // 384000 B
    float4* d4   = (float4*)(ws + 1152000);   // 1536000 B

    k1_fused <<<GRID_TOTAL, 256, 0, stream>>>(roi, gt, gtl, rpos, rneg,
                                              spos, sneg, lbl, d4, (float4*)out);
    k2_select<<<NB*2, 256, 0, stream>>>(spos, sneg, lbl, d4, out);
}